// Round 5
// baseline (468.158 us; speedup 1.0000x reference)
//
#include <hip/hip_runtime.h>
#include <hip/hip_cooperative_groups.h>
#include <stdint.h>

namespace cg = cooperative_groups;

// YoloNAS postprocess, fp32 in/out — single cooperative mega-kernel (R5).
// Phases: zero | conf/argmax (LDS-staged streaming) + hist | seg-sum | cutoff scan |
// candidate emit | bitonic sort + prep | IoU bit matrix | serial greedy sweep + output.
// Exact fp32 NMS arithmetic (no FMA contraction) — identical math to R4 (absmax 0).

#define N_ANCH   262144
#define N_CLS    80
#define K_TOP    1024
#define CAP      4096

// ---- workspace layout (bytes); total 341056 <= proven ws_size >= 733248 ----
#define OFF_SCAL  0           // u32[16]: [0]=cT, [2]=nsel, [3]=cand counter
#define OFF_HIST  64          // u32[32768]
#define OFF_SEG   131136      // u32[256] segment sums
#define OFF_LIST  132160      // u64[4096] sort keys
#define OFF_TB    164928      // f4[1024] top boxes
#define OFF_TC    181312      // f[1024] top conf
#define OFF_TL    185408      // f[1024] top label
#define OFF_OB    189504      // f4[1024] offset boxes
#define OFF_AREA  205888      // f[1024] areas
#define OFF_MASK  209984      // u64[1024*16] suppression bits
#define WS_REQUIRED 341056
#define ZERO_WORDS 33040      // scal + hist + seg

typedef unsigned long long ull;

__global__ __launch_bounds__(256) void k_sentinel(float* __restrict__ out, float v) {
    int i = blockIdx.x * 256 + threadIdx.x;
    if (i < K_TOP * 6) out[i] = v;
}

static __device__ __forceinline__ uint32_t conf_key24(float best) {
    uint32_t u = __float_as_uint(best);
    if (u > 0x3F800000u) u = 0x3F800000u;    // defensive; conf in [0.5, 1)
    if (u < 0x3F000000u) u = 0x3F000000u;
    return u - 0x3F000000u;                  // 0..0x800000, monotone in conf
}

static __device__ __forceinline__ uint32_t rl32(uint32_t v, int lane) {
    return (uint32_t)__builtin_amdgcn_readlane((int)v, lane);
}

__global__ __launch_bounds__(1024, 4) void k_fused(const float* __restrict__ scores,
                                                   const float* __restrict__ bboxes,
                                                   char* __restrict__ ws,
                                                   float* __restrict__ out) {
    __shared__ __align__(16) char smem[33024];
    cg::grid_group grid = cg::this_grid();
    const int b = blockIdx.x, t = threadIdx.x;

    uint32_t* scalU = (uint32_t*)(ws + OFF_SCAL);
    uint32_t* hist  = (uint32_t*)(ws + OFF_HIST);
    uint32_t* seg   = (uint32_t*)(ws + OFF_SEG);
    ull*      list  = (ull*)(ws + OFF_LIST);
    float4*   topB  = (float4*)(ws + OFF_TB);
    float*    topC  = (float*)(ws + OFF_TC);
    float*    topL  = (float*)(ws + OFF_TL);
    float4*   obG   = (float4*)(ws + OFF_OB);
    float*    areaG = (float*)(ws + OFF_AREA);
    ull*      maskG = (ull*)(ws + OFF_MASK);

    // ================= phase A: zero control + hist + seg =================
    {
        uint32_t g = (uint32_t)b * 1024u + (uint32_t)t;
        if (g < ZERO_WORDS) ((uint32_t*)ws)[g] = 0u;
    }
    grid.sync();

    // ====== phase B: conf/argmax, LDS-staged streaming; key kept in regs ======
    // block handles anchors [b*1024, +1024) in 16 sub-tiles of 64 anchors (20 KB each)
    float4* tile = (float4*)smem;                        // [64][21] f4, stride 336 B
    ull*    keys = (ull*)(smem + 21504);                 // [1024]
    {
        const float4* g4 = (const float4*)scores;
        const size_t base_f4 = (size_t)b * 1024u * 20u;
        const bool has2 = (t < 256);
        float4 r0, r1;
        r0 = g4[base_f4 + t];
        if (has2) r1 = g4[base_f4 + 1024 + t];
        const int row0 = t / 20, col0 = t % 20;
        const int j1 = 1024 + t, row1 = j1 / 20, col1 = j1 % 20;
        for (int st = 0; st < 16; st++) {
            __syncthreads();                             // prev compute done (buffer free)
            tile[row0 * 21 + col0] = r0;
            if (has2) tile[row1 * 21 + col1] = r1;
            __syncthreads();                             // staged
            if (st + 1 < 16) {                           // issue next loads (no wait here)
                size_t nb = base_f4 + (size_t)(st + 1) * 1280u;
                r0 = g4[nb + t];
                if (has2) r1 = g4[nb + 1024 + t];
            }
            // reduce: 64 rows x 16 lanes
            const int r = t >> 4, s = t & 15;
            const float4* rowp = tile + r * 21;
            float4 v0 = rowp[s];
            float best = v0.x; int lab = 4 * s;
            if (v0.y > best) { best = v0.y; lab = 4 * s + 1; }
            if (v0.z > best) { best = v0.z; lab = 4 * s + 2; }
            if (v0.w > best) { best = v0.w; lab = 4 * s + 3; }
            if (s < 4) {
                float4 v1 = rowp[16 + s];
                const int c0 = 64 + 4 * s;
                if (v1.x > best) { best = v1.x; lab = c0; }
                if (v1.y > best) { best = v1.y; lab = c0 + 1; }
                if (v1.z > best) { best = v1.z; lab = c0 + 2; }
                if (v1.w > best) { best = v1.w; lab = c0 + 3; }
            }
            // first-max tie-break: bigger conf, then smaller class
            ull key = ((ull)(uint32_t)__float_as_uint(best) << 7) | (ull)(uint32_t)(127 - lab);
            ull o;
            o = __shfl_xor(key, 1); if (o > key) key = o;
            o = __shfl_xor(key, 2); if (o > key) key = o;
            o = __shfl_xor(key, 4); if (o > key) key = o;
            o = __shfl_xor(key, 8); if (o > key) key = o;
            if (s == 0) keys[st * 64 + r] = key;
        }
        __syncthreads();
    }
    const ull mykey = keys[t];
    const float myconf = __uint_as_float((uint32_t)(mykey >> 7));
    const int mylab = 127 - (int)(mykey & 127);
    const uint32_t myk24 = conf_key24(myconf);
    uint32_t mybin = myk24 >> 8; if (mybin > 32767u) mybin = 32767u;
    const bool myvalid = (myconf >= 0.5f);
    if (myvalid) atomicAdd(&hist[mybin], 1u);
    grid.sync();

    // ================= phase C1: per-segment sums (128 bins/block) =================
    {
        uint32_t* s32 = (uint32_t*)smem;
        if (t < 128) s32[t] = hist[b * 128 + t];
        __syncthreads();
        for (int off = 64; off > 0; off >>= 1) {
            if (t < off) s32[t] += s32[t + off];
            __syncthreads();
        }
        if (t == 0) seg[b] = s32[0];
    }
    grid.sync();

    // ================= phase C2: cutoff bin (block 0) =================
    if (b == 0) {
        uint32_t* ls = (uint32_t*)smem;          // [0,256): seg copy; [256]: sc; [257]: above; [258]: total
        uint32_t* lh = (uint32_t*)smem + 272;    // [272, 400): crossing segment's bins
        if (t < 256) ls[t] = seg[t];
        __syncthreads();
        if (t == 0) {
            uint32_t total = 0;
            for (int s = 0; s < 256; s++) total += ls[s];
            uint32_t sc = 0, above = 0;
            if (total >= K_TOP) {
                uint32_t run = 0;
                for (int s = 255; s >= 0; s--) {
                    uint32_t c = ls[s];
                    if (run < K_TOP && run + c >= K_TOP) { sc = (uint32_t)s; above = run; break; }
                    run += c;
                }
            }
            ls[256] = sc; ls[257] = above; ls[258] = total;
        }
        __syncthreads();
        const uint32_t sc = ls[256];
        if (t < 128) lh[t] = hist[sc * 128 + t];
        __syncthreads();
        if (t == 0) {
            const uint32_t above = ls[257], total = ls[258];
            uint32_t cT = 0;
            if (total >= K_TOP) {
                uint32_t run = above;
                for (int i = 127; i >= 0; i--) {
                    uint32_t c = lh[i];
                    if (run < K_TOP && run + c >= K_TOP) { cT = ls[256] * 128 + (uint32_t)i; break; }
                    run += c;
                }
            }
            scalU[0] = cT;
            scalU[2] = (total < K_TOP) ? total : K_TOP;   // nsel
        }
    }
    grid.sync();

    // ================= phase D: candidate emit =================
    {
        const uint32_t cT = scalU[0];
        if (myvalid && mybin >= cT) {
            uint32_t slot = atomicAdd(&scalU[3], 1u);
            if (slot < CAP) {
                const uint32_t a = (uint32_t)b * 1024u + (uint32_t)t;
                list[slot] = ((ull)(0x1000000u - myk24) << 25) | ((ull)a << 7) | (ull)(uint32_t)mylab;
            }
        }
    }
    grid.sync();

    // ================= phase E: bitonic sort + top-K gather + prep (block 0) =================
    if (b == 0) {
        ull* sk = (ull*)smem;                    // [4096] = 32 KB
        uint32_t ncand = scalU[3]; if (ncand > CAP) ncand = CAP;
        const uint32_t nsel = scalU[2];
        for (int i = t; i < CAP; i += 1024) sk[i] = (i < (int)ncand) ? list[i] : ~0ull;
        __syncthreads();
        for (int k = 2; k <= CAP; k <<= 1) {
            for (int j = k >> 1; j > 0; j >>= 1) {
                #pragma unroll
                for (int r0 = 0; r0 < 4; r0++) {
                    int e = t + r0 * 1024;
                    int p = e ^ j;
                    if (p > e) {
                        ull x = sk[e], y = sk[p];
                        bool up = ((e & k) == 0);
                        if (up ? (x > y) : (x < y)) { sk[e] = y; sk[p] = x; }
                    }
                }
                __syncthreads();
            }
        }
        ull s = sk[t];
        __syncthreads();                         // everyone read before smem reuse (red)
        float4 bx = make_float4(0.f, 0.f, 0.f, 0.f);
        float cf = 0.f, lb = 0.f;
        if ((uint32_t)t < nsel) {
            uint32_t idx  = (uint32_t)(s >> 7) & 0x3FFFFu;
            uint32_t lab  = (uint32_t)s & 127u;
            uint32_t keyp = (uint32_t)(s >> 25);
            cf = __uint_as_float(0x3F000000u + (0x1000000u - keyp));
            lb = (float)lab;
            bx = ((const float4*)bboxes)[idx];
        }
        topB[t] = bx; topC[t] = cf; topL[t] = lb;
        // fused prep: max_coord, offset boxes, areas (exact reference fp32 order)
        float* red = (float*)smem;
        red[t] = fmaxf(fmaxf(bx.x, bx.y), fmaxf(bx.z, bx.w));
        __syncthreads();
        for (int off = 512; off > 0; off >>= 1) {
            if (t < off) red[t] = fmaxf(red[t], red[t + off]);
            __syncthreads();
        }
        float M = __fadd_rn(red[0], 1.0f);
        float o = __fmul_rn(lb, M);
        float4 q;
        q.x = __fadd_rn(bx.x, o); q.y = __fadd_rn(bx.y, o);
        q.z = __fadd_rn(bx.z, o); q.w = __fadd_rn(bx.w, o);
        obG[t] = q;
        areaG[t] = __fmul_rn(__fsub_rn(q.z, q.x), __fsub_rn(q.w, q.y));
    }
    grid.sync();

    // ================= phase F: IoU suppression bit matrix (blocks 0..15) =================
    if (b < 16) {
        float4* sob = (float4*)smem;             // [1024] = 16 KB
        float*  sar = (float*)(smem + 16384);    // [1024] = 4 KB
        sob[t] = obG[t];
        sar[t] = areaG[t];
        __syncthreads();
        const int i = (b << 6) + (t >> 4);       // 64 rows per block
        const int w = t & 15;
        const float4 bi = sob[i];
        const float  ai = sar[i];
        ull word = 0;
        const int j0 = w * 64;
        #pragma unroll 8
        for (int bit = 0; bit < 64; bit++) {
            const int j = j0 + bit;
            if (j > i) {
                float4 bj = sob[j];
                float lx = fmaxf(bi.x, bj.x), ly = fmaxf(bi.y, bj.y);
                float rx = fminf(bi.z, bj.z), ry = fminf(bi.w, bj.w);
                float wx = fmaxf(__fsub_rn(rx, lx), 0.f);
                float wy = fmaxf(__fsub_rn(ry, ly), 0.f);
                float inter = __fmul_rn(wx, wy);
                float uni = __fsub_rn(__fadd_rn(ai, sar[j]), inter);
                float iou = __fdiv_rn(inter, fmaxf(uni, 1e-9f));
                if (iou > 0.6f) word |= 1ull << bit;
            }
        }
        maskG[i * 16 + w] = word;
    }
    grid.sync();

    // ================= phase G: serial greedy sweep + output (block 0) =================
    if (b == 0) {
        ull* chunk = (ull*)smem;                 // [4096] = 32 KB
        ull* keepw = (ull*)(smem + 32768);       // [16]
        const uint32_t nsel = scalU[2];
        ull kw = 0;
        if (t < 16) {
            int lo = t * 64;
            kw = (nsel >= (uint32_t)(lo + 64)) ? ~0ull
               : ((nsel <= (uint32_t)lo) ? 0ull : ((1ull << (nsel - lo)) - 1ull));
        }
        for (int c = 0; c < 4; c++) {
            const ull* src = maskG + c * 4096;
            #pragma unroll
            for (int k = 0; k < 4; k++) chunk[k * 1024 + t] = src[k * 1024 + t];
            __syncthreads();
            if (t < 16) {
                const int i0 = c * 256;
                #pragma unroll 8
                for (int i = i0; i < i0 + 256; i++) {
                    const int wi = i >> 6;
                    uint32_t lo32 = rl32((uint32_t)(kw & 0xFFFFFFFFull), wi);
                    uint32_t hi32 = rl32((uint32_t)(kw >> 32), wi);
                    ull cur = ((ull)hi32 << 32) | lo32;
                    ull bi = (cur >> (i & 63)) & 1ull;
                    ull m = chunk[(i & 255) * 16 + t];
                    kw &= ~(m & (0ull - bi));    // apply row i's suppression iff keep[i]
                }
            }
            __syncthreads();
        }
        if (t < 16) keepw[t] = kw;
        __syncthreads();
        const bool keep = (keepw[t >> 6] >> (t & 63)) & 1ull;
        float4 bx = topB[t];
        float v0 = keep ? bx.x : 0.f, v1 = keep ? bx.y : 0.f;
        float v2 = keep ? bx.z : 0.f, v3 = keep ? bx.w : 0.f;
        float v4 = keep ? topC[t] : 0.f, v5 = keep ? topL[t] : 0.f;
        float2* o2 = (float2*)out;
        o2[t * 3 + 0] = make_float2(v0, v1);
        o2[t * 3 + 1] = make_float2(v2, v3);
        o2[t * 3 + 2] = make_float2(v4, v5);
    }
}

extern "C" void kernel_launch(void* const* d_in, const int* in_sizes, int n_in,
                              void* d_out, int out_size, void* d_ws, size_t ws_size,
                              hipStream_t stream) {
    const float* bboxes = (const float*)d_in[0];
    const float* scores = (const float*)d_in[1];
    if (n_in >= 2 && in_sizes[0] > in_sizes[1]) {   // defensive: scores is the 20x larger input
        bboxes = (const float*)d_in[1];
        scores = (const float*)d_in[0];
    }

    if (ws_size < (size_t)WS_REQUIRED) {
        k_sentinel<<<(K_TOP * 6 + 255) / 256, 256, 0, stream>>>(
            (float*)d_out, (float)(ws_size >> 10));
        return;
    }

    char* ws = (char*)d_ws;
    float* outp = (float*)d_out;
    void* args[] = { (void*)&scores, (void*)&bboxes, (void*)&ws, (void*)&outp };
    hipLaunchCooperativeKernel((const void*)k_fused, dim3(256), dim3(1024),
                               args, 0, stream);
}